// Round 3
// baseline (340.410 us; speedup 1.0000x reference)
//
#include <hip/hip_runtime.h>

#define Bb 64
#define Tt 256
#define Hh 512
#define Ww 1024
#define HW (Hh * Ww)          // 524288
#define EPSF 1e-5f

#define RB 2048               // one block per 16384-float chunk; grid == RB
#define CHUNK 16384           // svf floats owned per block (32 blocks/batch)

typedef float vf4 __attribute__((ext_vector_type(4)));

// ws layout:
//   [0,256)         int    count[64]
//   [256,768)       double vdot[64]
//   [768,17152)     double esum_p[2048]
//   [17152,33536)   double edot_p[2048]
// Everything is written before it is read -> no ws memset needed.

// ---------------------------------------------------------------------------
// Point computation (bit-identical to the reference at fp32)
// ---------------------------------------------------------------------------
__device__ __forceinline__ void comp_pt(const float* __restrict__ gt, int b,
                                        int idx, int ms, int segN,
                                        float& px, float& py) {
    if (idx < segN) {
        int seg = idx / ms;
        int k = idx - seg * ms;
        const float* g0 = gt + (size_t)(b * Tt + seg) * 9;
        float sx = g0[2] * 0.5f, sy = g0[5] * 0.5f;
        float ex = g0[11] * 0.5f, ey = g0[14] * 0.5f;
        float t = (ms > 1) ? (float)k / (float)(ms - 1) : 0.0f;
        px = __fadd_rn(sx, __fmul_rn(t, __fsub_rn(ex, sx)));
        py = __fadd_rn(sy, __fmul_rn(t, __fsub_rn(ey, sy)));
    } else {
        const float* g0 = gt + (size_t)(b * Tt + (Tt - 1)) * 9;
        px = g0[2] * 0.5f;
        py = g0[5] * 0.5f;
    }
}

__device__ __forceinline__ int pt_cell(float px, float py) {
    int xi = (int)fminf(fmaxf(px, 0.0f), (float)(Hh - 1));
    int yi = (int)fminf(fmaxf(py, 0.0f), (float)(Ww - 1));
    return xi * Ww + yi;
}

// ---------------------------------------------------------------------------
// Combined kernel: grid = 2048 blocks exactly (8 blocks/CU, one generation).
// Block (b = blk>>5, c = blk&31) owns svf chunk [c*16384, (c+1)*16384) of
// batch b.
//   phase 0: NT zero-fill of the chunk (nontemporal: the output stream must
//            not evict the iteration-invariant 268 MB of inputs from the
//            256 MB Infinity Cache; FETCH_SIZE is the diagnostic).
//   phase 1: streaming exps/rew reduce over the same range.
//   phase 2: per-batch dedup count (cells are monotone -> adjacent-compare);
//            the designated block per batch (c == b&31) also writes pts and
//            gathers vdot -- folded here so the grid has no tail blocks.
//   barrier (drains NT fill stores via vmcnt(0)), then
//   phase 3: NT write of recip at visited cells inside this chunk.
// Chunks are disjoint -> no atomics, no cross-block races.
// ---------------------------------------------------------------------------
__global__ __launch_bounds__(256) void combined_kernel(
        const float* __restrict__ exps, const float* __restrict__ rew,
        const float* __restrict__ gt,
        float* __restrict__ pts, float* __restrict__ svf,
        double* __restrict__ esum_p, double* __restrict__ edot_p,
        int* __restrict__ count_out, double* __restrict__ vdot_out,
        int ms, int P) {
    int blk = blockIdx.x;
    int b = blk >> 5;
    int c = blk & 31;
    bool isScat = (c == (b & 31));   // designated scatter block for batch b
    int segN = (Tt - 1) * ms;
    size_t base = (size_t)b * HW + (size_t)c * CHUNK;

    // ---- phase 0: NT zero-fill (fire-and-forget; drains at the barrier).
    // svf = out+1 is only 4B-aligned: peel head/tail scalars around the
    // aligned vf4 body.
    {
        float* p = svf + base;
        int head = (int)((16 - ((uintptr_t)p & 15)) & 15) >> 2;  // 0..3
        int nv   = (CHUNK - head) >> 2;
        int tail = CHUNK - head - (nv << 2);
        if ((int)threadIdx.x < head)
            __builtin_nontemporal_store(0.0f, p + threadIdx.x);
        if ((int)threadIdx.x < tail)
            __builtin_nontemporal_store(0.0f, p + head + (nv << 2) + threadIdx.x);
        vf4* v4 = (vf4*)(p + head);
        vf4 z = {0.0f, 0.0f, 0.0f, 0.0f};
        for (int k = (int)threadIdx.x; k < nv; k += 256)
            __builtin_nontemporal_store(z, v4 + k);
    }

    // ---- phase 1: streaming reduce (arithmetic identical to prior rounds)
    float es = 0.0f, ed = 0.0f;
    #pragma unroll
    for (int j = 0; j < 2; ++j) {
        const vf4* e4 = (const vf4*)(exps + base) + j * 2048 + threadIdx.x;
        const vf4* r4 = (const vf4*)(rew  + base) + j * 2048 + threadIdx.x;
        vf4 ev[8], rv[8];
        #pragma unroll
        for (int k = 0; k < 8; ++k) ev[k] = e4[k * 256];
        #pragma unroll
        for (int k = 0; k < 8; ++k) rv[k] = r4[k * 256];
        #pragma unroll
        for (int k = 0; k < 8; ++k) {
            vf4 e = ev[k], r = rv[k];
            es += (e.x + e.y) + (e.z + e.w);
            ed += (e.x * r.x + e.y * r.y) + (e.z * r.z + e.w * r.w);
        }
    }
    for (int off = 32; off; off >>= 1) {
        es += __shfl_down(es, off);
        ed += __shfl_down(ed, off);
    }

    // ---- phase 2: per-batch dedup count; designated block also scatters pts
    // and gathers vdot (identical arithmetic to the old scatter blocks).
    int myCount = 0;
    float myV = 0.0f;
    for (int idx = threadIdx.x; idx < P; idx += 256) {
        float px, py;
        comp_pt(gt, b, idx, ms, segN, px, py);
        int cell = pt_cell(px, py);
        bool claim;
        if (idx == 0) {
            claim = true;
        } else {
            float qx, qy;
            comp_pt(gt, b, idx - 1, ms, segN, qx, qy);
            claim = (pt_cell(qx, qy) != cell);
        }
        myCount += claim ? 1 : 0;
        if (isScat) {
            size_t pi = ((size_t)b * P + idx) * 2;
            __builtin_nontemporal_store(px, pts + pi);
            __builtin_nontemporal_store(py, pts + pi + 1);
            if (claim) myV += rew[(size_t)b * HW + cell];
        }
    }
    for (int off = 32; off; off >>= 1) {
        myCount += __shfl_down(myCount, off);
        myV     += __shfl_down(myV, off);
    }

    __shared__ float s_es[4], s_ed[4];
    __shared__ float sv[4];
    __shared__ int   sc2[4];
    int lane = threadIdx.x & 63, wv = threadIdx.x >> 6;
    if (lane == 0) { s_es[wv] = es; s_ed[wv] = ed; sc2[wv] = myCount; sv[wv] = myV; }
    __syncthreads();   // publishes LDS partials AND drains phase-0 NT stores
    if (threadIdx.x == 0) {
        esum_p[blk] = (double)((s_es[0] + s_es[1]) + (s_es[2] + s_es[3]));
        edot_p[blk] = (double)((s_ed[0] + s_ed[1]) + (s_ed[2] + s_ed[3]));
        if (isScat) {
            int tot  = (sc2[0] + sc2[1]) + (sc2[2] + sc2[3]);
            float tv = (sv[0] + sv[1]) + (sv[2] + sv[3]);
            count_out[b] = tot;
            vdot_out[b]  = (double)tv;
        }
    }
    int tot = (sc2[0] + sc2[1]) + (sc2[2] + sc2[3]);
    float recip = 1.0f / ((float)tot + EPSF);

    // ---- phase 3: NT write recip at visited cells inside this chunk
    // (duplicates write the identical value; zeros already laid down)
    int lo = c * CHUNK, hi = lo + CHUNK;
    for (int idx = threadIdx.x; idx < P; idx += 256) {
        float px, py;
        comp_pt(gt, b, idx, ms, segN, px, py);
        int cell = pt_cell(px, py);
        if (cell >= lo && cell < hi)
            __builtin_nontemporal_store(recip, svf + (size_t)b * HW + cell);
    }
}

// ---------------------------------------------------------------------------
// Loss kernel
// ---------------------------------------------------------------------------
__global__ void loss_kernel(const double* __restrict__ esum_p,
                            const double* __restrict__ edot_p,
                            const double* __restrict__ vdot,
                            const int* __restrict__ count,
                            float* __restrict__ loss_out) {
    int b = threadIdx.x;  // 64 threads = 1 wave
    double es = 0.0, ed = 0.0;
    #pragma unroll 8
    for (int c = 0; c < 32; ++c) {
        es += esum_p[b * 32 + c];
        ed += edot_p[b * 32 + c];
    }
    double e = ed / (es + 1e-5);
    double v = vdot[b] / ((double)count[b] + 1e-5);
    double term = e - v;
    for (int off = 32; off; off >>= 1) term += __shfl_down(term, off);
    if (b == 0) loss_out[0] = (float)(term / (double)Bb);
}

extern "C" void kernel_launch(void* const* d_in, const int* in_sizes, int n_in,
                              void* d_out, int out_size, void* d_ws, size_t ws_size,
                              hipStream_t stream) {
    const float* gt   = (const float*)d_in[0];
    const float* exps = (const float*)d_in[1];
    const float* rew  = (const float*)d_in[2];
    float* out = (float*)d_out;

    float* loss_out = out;
    float* svf = out + 1;
    int P  = (out_size - 1 - Bb * HW) / (Bb * 2);
    int ms = (P - 1) / (Tt - 1);
    float* pts = out + 1 + (size_t)Bb * HW;

    int*    count  = (int*)d_ws;
    double* vdot   = (double*)((char*)d_ws + 256);
    double* esum_p = (double*)((char*)d_ws + 768);
    double* edot_p = (double*)((char*)d_ws + 17152);

    combined_kernel<<<RB, 256, 0, stream>>>(exps, rew, gt, pts, svf,
                                            esum_p, edot_p, count, vdot,
                                            ms, P);
    loss_kernel<<<1, 64, 0, stream>>>(esum_p, edot_p, vdot, count, loss_out);
}

// Round 4
// 327.964 us; speedup vs baseline: 1.0379x; 1.0379x over previous
//
#include <hip/hip_runtime.h>

#define Bb 64
#define Tt 256
#define Hh 512
#define Ww 1024
#define HW (Hh * Ww)          // 524288
#define EPSF 1e-5f

#define RB 2048               // one block per 16384-float chunk; grid == RB
#define CHUNK 16384           // svf floats owned per block (32 blocks/batch)

typedef float vf4 __attribute__((ext_vector_type(4)));

// ws layout:
//   [0,256)         int    count[64]
//   [256,768)       double vdot[64]
//   [768,17152)     double esum_p[2048]
//   [17152,33536)   double edot_p[2048]
// Everything is written before it is read -> no ws memset needed.

// ---------------------------------------------------------------------------
// Point computation (bit-identical to the reference at fp32)
// ---------------------------------------------------------------------------
__device__ __forceinline__ void comp_pt(const float* __restrict__ gt, int b,
                                        int idx, int ms, int segN,
                                        float& px, float& py) {
    if (idx < segN) {
        int seg = idx / ms;
        int k = idx - seg * ms;
        const float* g0 = gt + (size_t)(b * Tt + seg) * 9;
        float sx = g0[2] * 0.5f, sy = g0[5] * 0.5f;
        float ex = g0[11] * 0.5f, ey = g0[14] * 0.5f;
        float t = (ms > 1) ? (float)k / (float)(ms - 1) : 0.0f;
        px = __fadd_rn(sx, __fmul_rn(t, __fsub_rn(ex, sx)));
        py = __fadd_rn(sy, __fmul_rn(t, __fsub_rn(ey, sy)));
    } else {
        const float* g0 = gt + (size_t)(b * Tt + (Tt - 1)) * 9;
        px = g0[2] * 0.5f;
        py = g0[5] * 0.5f;
    }
}

__device__ __forceinline__ int pt_cell(float px, float py) {
    int xi = (int)fminf(fmaxf(px, 0.0f), (float)(Hh - 1));
    int yi = (int)fminf(fmaxf(py, 0.0f), (float)(Ww - 1));
    return xi * Ww + yi;
}

// ---------------------------------------------------------------------------
// Combined kernel: grid = 2048 blocks exactly (8 blocks/CU, one generation).
// Block (b = blk>>5, c = blk&31) owns svf chunk [c*16384, (c+1)*16384) of
// batch b.
// PHASE ORDER MATTERS (vmcnt retires in issue order): the streaming reduce
// loads are issued FIRST so no load consumption ever waits behind fill-store
// drain (round 3 measured +20us when NT stores lengthened that drain; NT is
// also reverted -- it did not move FETCH_SIZE and only added latency).
//   phase A: streaming exps/rew reduce (pure loads).
//   phase B: plain zero-fill of the chunk (stores drain under phase C + bar).
//   phase C: per-batch dedup count (cells are monotone -> adjacent-compare);
//            the designated block per batch (c == b&31) also writes pts and
//            gathers vdot.
//   barrier (publishes LDS partials AND drains phase-B stores), then
//   phase D: write recip at visited cells inside this chunk.
// Chunks are disjoint -> no atomics, no cross-block races.
// ---------------------------------------------------------------------------
__global__ __launch_bounds__(256) void combined_kernel(
        const float* __restrict__ exps, const float* __restrict__ rew,
        const float* __restrict__ gt,
        float* __restrict__ pts, float* __restrict__ svf,
        double* __restrict__ esum_p, double* __restrict__ edot_p,
        int* __restrict__ count_out, double* __restrict__ vdot_out,
        int ms, int P) {
    int blk = blockIdx.x;
    int b = blk >> 5;
    int c = blk & 31;
    bool isScat = (c == (b & 31));   // designated scatter block for batch b
    int segN = (Tt - 1) * ms;
    size_t base = (size_t)b * HW + (size_t)c * CHUNK;

    // ---- phase A: streaming reduce (loads first; arithmetic identical to
    // all prior rounds -> absmax stays 0)
    float es = 0.0f, ed = 0.0f;
    #pragma unroll
    for (int j = 0; j < 2; ++j) {
        const vf4* e4 = (const vf4*)(exps + base) + j * 2048 + threadIdx.x;
        const vf4* r4 = (const vf4*)(rew  + base) + j * 2048 + threadIdx.x;
        vf4 ev[8], rv[8];
        #pragma unroll
        for (int k = 0; k < 8; ++k) ev[k] = e4[k * 256];
        #pragma unroll
        for (int k = 0; k < 8; ++k) rv[k] = r4[k * 256];
        #pragma unroll
        for (int k = 0; k < 8; ++k) {
            vf4 e = ev[k], r = rv[k];
            es += (e.x + e.y) + (e.z + e.w);
            ed += (e.x * r.x + e.y * r.y) + (e.z * r.z + e.w * r.w);
        }
    }
    for (int off = 32; off; off >>= 1) {
        es += __shfl_down(es, off);
        ed += __shfl_down(ed, off);
    }

    // ---- phase B: plain zero-fill (fire-and-forget; drains during phase C
    // and the barrier). svf = out+1 is only 4B-aligned: peel head/tail
    // scalars around the aligned vf4 body.
    {
        float* p = svf + base;
        int head = (int)((16 - ((uintptr_t)p & 15)) & 15) >> 2;  // 0..3
        int nv   = (CHUNK - head) >> 2;
        int tail = CHUNK - head - (nv << 2);
        if ((int)threadIdx.x < head) p[threadIdx.x] = 0.0f;
        if ((int)threadIdx.x < tail) p[head + (nv << 2) + threadIdx.x] = 0.0f;
        vf4* v4 = (vf4*)(p + head);
        vf4 z = {0.0f, 0.0f, 0.0f, 0.0f};
        for (int k = (int)threadIdx.x; k < nv; k += 256) v4[k] = z;
    }

    // ---- phase C: per-batch dedup count; designated block also scatters pts
    // and gathers vdot (identical arithmetic to prior rounds).
    int myCount = 0;
    float myV = 0.0f;
    for (int idx = threadIdx.x; idx < P; idx += 256) {
        float px, py;
        comp_pt(gt, b, idx, ms, segN, px, py);
        int cell = pt_cell(px, py);
        bool claim;
        if (idx == 0) {
            claim = true;
        } else {
            float qx, qy;
            comp_pt(gt, b, idx - 1, ms, segN, qx, qy);
            claim = (pt_cell(qx, qy) != cell);
        }
        myCount += claim ? 1 : 0;
        if (isScat) {
            size_t pi = ((size_t)b * P + idx) * 2;
            pts[pi]     = px;
            pts[pi + 1] = py;
            if (claim) myV += rew[(size_t)b * HW + cell];
        }
    }
    for (int off = 32; off; off >>= 1) {
        myCount += __shfl_down(myCount, off);
        myV     += __shfl_down(myV, off);
    }

    __shared__ float s_es[4], s_ed[4];
    __shared__ float sv[4];
    __shared__ int   sc2[4];
    int lane = threadIdx.x & 63, wv = threadIdx.x >> 6;
    if (lane == 0) { s_es[wv] = es; s_ed[wv] = ed; sc2[wv] = myCount; sv[wv] = myV; }
    __syncthreads();   // publishes LDS partials AND drains phase-B stores
    if (threadIdx.x == 0) {
        esum_p[blk] = (double)((s_es[0] + s_es[1]) + (s_es[2] + s_es[3]));
        edot_p[blk] = (double)((s_ed[0] + s_ed[1]) + (s_ed[2] + s_ed[3]));
        if (isScat) {
            int tot  = (sc2[0] + sc2[1]) + (sc2[2] + sc2[3]);
            float tv = (sv[0] + sv[1]) + (sv[2] + sv[3]);
            count_out[b] = tot;
            vdot_out[b]  = (double)tv;
        }
    }
    int tot = (sc2[0] + sc2[1]) + (sc2[2] + sc2[3]);
    float recip = 1.0f / ((float)tot + EPSF);

    // ---- phase D: write recip at visited cells inside this chunk
    // (duplicates write the identical value; zeros already laid down)
    int lo = c * CHUNK, hi = lo + CHUNK;
    for (int idx = threadIdx.x; idx < P; idx += 256) {
        float px, py;
        comp_pt(gt, b, idx, ms, segN, px, py);
        int cell = pt_cell(px, py);
        if (cell >= lo && cell < hi)
            svf[(size_t)b * HW + cell] = recip;
    }
}

// ---------------------------------------------------------------------------
// Loss kernel
// ---------------------------------------------------------------------------
__global__ void loss_kernel(const double* __restrict__ esum_p,
                            const double* __restrict__ edot_p,
                            const double* __restrict__ vdot,
                            const int* __restrict__ count,
                            float* __restrict__ loss_out) {
    int b = threadIdx.x;  // 64 threads = 1 wave
    double es = 0.0, ed = 0.0;
    #pragma unroll 8
    for (int c = 0; c < 32; ++c) {
        es += esum_p[b * 32 + c];
        ed += edot_p[b * 32 + c];
    }
    double e = ed / (es + 1e-5);
    double v = vdot[b] / ((double)count[b] + 1e-5);
    double term = e - v;
    for (int off = 32; off; off >>= 1) term += __shfl_down(term, off);
    if (b == 0) loss_out[0] = (float)(term / (double)Bb);
}

extern "C" void kernel_launch(void* const* d_in, const int* in_sizes, int n_in,
                              void* d_out, int out_size, void* d_ws, size_t ws_size,
                              hipStream_t stream) {
    const float* gt   = (const float*)d_in[0];
    const float* exps = (const float*)d_in[1];
    const float* rew  = (const float*)d_in[2];
    float* out = (float*)d_out;

    float* loss_out = out;
    float* svf = out + 1;
    int P  = (out_size - 1 - Bb * HW) / (Bb * 2);
    int ms = (P - 1) / (Tt - 1);
    float* pts = out + 1 + (size_t)Bb * HW;

    int*    count  = (int*)d_ws;
    double* vdot   = (double*)((char*)d_ws + 256);
    double* esum_p = (double*)((char*)d_ws + 768);
    double* edot_p = (double*)((char*)d_ws + 17152);

    combined_kernel<<<RB, 256, 0, stream>>>(exps, rew, gt, pts, svf,
                                            esum_p, edot_p, count, vdot,
                                            ms, P);
    loss_kernel<<<1, 64, 0, stream>>>(esum_p, edot_p, vdot, count, loss_out);
}

// Round 5
// 319.799 us; speedup vs baseline: 1.0644x; 1.0255x over previous
//
#include <hip/hip_runtime.h>

#define Bb 64
#define Tt 256
#define Hh 512
#define Ww 1024
#define HW (Hh * Ww)          // 524288
#define EPSF 1e-5f

#define RB 4096               // one block per 8192-float chunk; 2 generations
#define CHUNK 8192            // svf floats owned per block (64 blocks/batch)

typedef float vf4 __attribute__((ext_vector_type(4)));

// ws layout (byte-identical footprint to prior rounds):
//   [0,256)         int    count[64]
//   [256,768)       double vdot[64]
//   [768,17152)     float  esum_p[4096]   (float partials are EXACT: each is
//   [17152,33536)   float  edot_p[4096]    itself a block-computed fp32 value)
// Everything is written before it is read -> no ws memset needed.

// ---------------------------------------------------------------------------
// Point computation (bit-identical to the reference at fp32)
// ---------------------------------------------------------------------------
__device__ __forceinline__ void comp_pt(const float* __restrict__ gt, int b,
                                        int idx, int ms, int segN,
                                        float& px, float& py) {
    if (idx < segN) {
        int seg = idx / ms;
        int k = idx - seg * ms;
        const float* g0 = gt + (size_t)(b * Tt + seg) * 9;
        float sx = g0[2] * 0.5f, sy = g0[5] * 0.5f;
        float ex = g0[11] * 0.5f, ey = g0[14] * 0.5f;
        float t = (ms > 1) ? (float)k / (float)(ms - 1) : 0.0f;
        px = __fadd_rn(sx, __fmul_rn(t, __fsub_rn(ex, sx)));
        py = __fadd_rn(sy, __fmul_rn(t, __fsub_rn(ey, sy)));
    } else {
        const float* g0 = gt + (size_t)(b * Tt + (Tt - 1)) * 9;
        px = g0[2] * 0.5f;
        py = g0[5] * 0.5f;
    }
}

__device__ __forceinline__ int pt_cell(float px, float py) {
    int xi = (int)fminf(fmaxf(px, 0.0f), (float)(Hh - 1));
    int yi = (int)fminf(fmaxf(py, 0.0f), (float)(Ww - 1));
    return xi * Ww + yi;
}

// ---------------------------------------------------------------------------
// Combined kernel: grid = 4096 blocks = TWO generations (16 blocks/CU total,
// 8 resident). Rationale vs the one-generation round-4 kernel (122 us):
//   - grid == capacity left no backfill for drain imbalance (Occupancy 66%);
//   - all blocks marched through phases in lockstep, so the read path idled
//     during the chip-wide store-drain window. With 2 generations, gen-2
//     read bursts overlap gen-1 store drains -> mixed HBM traffic, pushing
//     toward the measured pure-read floor (~107 us for 268 MB).
// Block (b = blk>>6, c = blk&63) owns svf chunk [c*8192, (c+1)*8192) of
// batch b. Phase order preserved from round 4 (loads first; stores drain
// under ALU + barrier; NT stores stay reverted -- they cost 20 us).
//   phase A: streaming exps/rew reduce (pure loads, 8 float4 per stream).
//   phase B: plain zero-fill of the chunk.
//   phase C: per-batch dedup count (cells monotone -> adjacent-compare);
//            designated block (c == b) also writes pts and gathers vdot.
//   barrier (publishes LDS partials AND drains phase-B stores), then
//   phase D: write recip at visited cells inside this chunk.
// Chunks are disjoint -> no atomics, no cross-block races.
// ---------------------------------------------------------------------------
__global__ __launch_bounds__(256) void combined_kernel(
        const float* __restrict__ exps, const float* __restrict__ rew,
        const float* __restrict__ gt,
        float* __restrict__ pts, float* __restrict__ svf,
        float* __restrict__ esum_p, float* __restrict__ edot_p,
        int* __restrict__ count_out, double* __restrict__ vdot_out,
        int ms, int P) {
    int blk = blockIdx.x;
    int b = blk >> 6;
    int c = blk & 63;
    bool isScat = (c == b);          // designated scatter block for batch b
    int segN = (Tt - 1) * ms;
    size_t base = (size_t)b * HW + (size_t)c * CHUNK;

    // ---- phase A: streaming reduce (loads first; per-thread arithmetic
    // identical in kind to prior rounds, grouping per 8192-chunk)
    float es = 0.0f, ed = 0.0f;
    {
        const vf4* e4 = (const vf4*)(exps + base) + threadIdx.x;
        const vf4* r4 = (const vf4*)(rew  + base) + threadIdx.x;
        vf4 ev[8], rv[8];
        #pragma unroll
        for (int k = 0; k < 8; ++k) ev[k] = e4[k * 256];
        #pragma unroll
        for (int k = 0; k < 8; ++k) rv[k] = r4[k * 256];
        #pragma unroll
        for (int k = 0; k < 8; ++k) {
            vf4 e = ev[k], r = rv[k];
            es += (e.x + e.y) + (e.z + e.w);
            ed += (e.x * r.x + e.y * r.y) + (e.z * r.z + e.w * r.w);
        }
    }
    for (int off = 32; off; off >>= 1) {
        es += __shfl_down(es, off);
        ed += __shfl_down(ed, off);
    }

    // ---- phase B: plain zero-fill (fire-and-forget; drains during phase C,
    // the barrier, and other blocks' phase A). svf = out+1 is only
    // 4B-aligned: peel head/tail scalars around the aligned vf4 body.
    {
        float* p = svf + base;
        int head = (int)((16 - ((uintptr_t)p & 15)) & 15) >> 2;  // 0..3
        int nv   = (CHUNK - head) >> 2;
        int tail = CHUNK - head - (nv << 2);
        if ((int)threadIdx.x < head) p[threadIdx.x] = 0.0f;
        if ((int)threadIdx.x < tail) p[head + (nv << 2) + threadIdx.x] = 0.0f;
        vf4* v4 = (vf4*)(p + head);
        vf4 z = {0.0f, 0.0f, 0.0f, 0.0f};
        for (int k = (int)threadIdx.x; k < nv; k += 256) v4[k] = z;
    }

    // ---- phase C: per-batch dedup count; designated block also scatters pts
    // and gathers vdot (identical arithmetic to prior rounds).
    int myCount = 0;
    float myV = 0.0f;
    for (int idx = threadIdx.x; idx < P; idx += 256) {
        float px, py;
        comp_pt(gt, b, idx, ms, segN, px, py);
        int cell = pt_cell(px, py);
        bool claim;
        if (idx == 0) {
            claim = true;
        } else {
            float qx, qy;
            comp_pt(gt, b, idx - 1, ms, segN, qx, qy);
            claim = (pt_cell(qx, qy) != cell);
        }
        myCount += claim ? 1 : 0;
        if (isScat) {
            size_t pi = ((size_t)b * P + idx) * 2;
            pts[pi]     = px;
            pts[pi + 1] = py;
            if (claim) myV += rew[(size_t)b * HW + cell];
        }
    }
    for (int off = 32; off; off >>= 1) {
        myCount += __shfl_down(myCount, off);
        myV     += __shfl_down(myV, off);
    }

    __shared__ float s_es[4], s_ed[4];
    __shared__ float sv[4];
    __shared__ int   sc2[4];
    int lane = threadIdx.x & 63, wv = threadIdx.x >> 6;
    if (lane == 0) { s_es[wv] = es; s_ed[wv] = ed; sc2[wv] = myCount; sv[wv] = myV; }
    __syncthreads();   // publishes LDS partials AND drains phase-B stores
    if (threadIdx.x == 0) {
        esum_p[blk] = (s_es[0] + s_es[1]) + (s_es[2] + s_es[3]);
        edot_p[blk] = (s_ed[0] + s_ed[1]) + (s_ed[2] + s_ed[3]);
        if (isScat) {
            int tot  = (sc2[0] + sc2[1]) + (sc2[2] + sc2[3]);
            float tv = (sv[0] + sv[1]) + (sv[2] + sv[3]);
            count_out[b] = tot;
            vdot_out[b]  = (double)tv;
        }
    }
    int tot = (sc2[0] + sc2[1]) + (sc2[2] + sc2[3]);
    float recip = 1.0f / ((float)tot + EPSF);

    // ---- phase D: write recip at visited cells inside this chunk
    // (duplicates write the identical value; zeros already laid down)
    int lo = c * CHUNK, hi = lo + CHUNK;
    for (int idx = threadIdx.x; idx < P; idx += 256) {
        float px, py;
        comp_pt(gt, b, idx, ms, segN, px, py);
        int cell = pt_cell(px, py);
        if (cell >= lo && cell < hi)
            svf[(size_t)b * HW + cell] = recip;
    }
}

// ---------------------------------------------------------------------------
// Loss kernel (64 float partials per batch now; accumulation stays double)
// ---------------------------------------------------------------------------
__global__ void loss_kernel(const float* __restrict__ esum_p,
                            const float* __restrict__ edot_p,
                            const double* __restrict__ vdot,
                            const int* __restrict__ count,
                            float* __restrict__ loss_out) {
    int b = threadIdx.x;  // 64 threads = 1 wave
    double es = 0.0, ed = 0.0;
    #pragma unroll 8
    for (int c = 0; c < 64; ++c) {
        es += (double)esum_p[b * 64 + c];
        ed += (double)edot_p[b * 64 + c];
    }
    double e = ed / (es + 1e-5);
    double v = vdot[b] / ((double)count[b] + 1e-5);
    double term = e - v;
    for (int off = 32; off; off >>= 1) term += __shfl_down(term, off);
    if (b == 0) loss_out[0] = (float)(term / (double)Bb);
}

extern "C" void kernel_launch(void* const* d_in, const int* in_sizes, int n_in,
                              void* d_out, int out_size, void* d_ws, size_t ws_size,
                              hipStream_t stream) {
    const float* gt   = (const float*)d_in[0];
    const float* exps = (const float*)d_in[1];
    const float* rew  = (const float*)d_in[2];
    float* out = (float*)d_out;

    float* loss_out = out;
    float* svf = out + 1;
    int P  = (out_size - 1 - Bb * HW) / (Bb * 2);
    int ms = (P - 1) / (Tt - 1);
    float* pts = out + 1 + (size_t)Bb * HW;

    int*    count  = (int*)d_ws;
    double* vdot   = (double*)((char*)d_ws + 256);
    float*  esum_p = (float*)((char*)d_ws + 768);
    float*  edot_p = (float*)((char*)d_ws + 17152);

    combined_kernel<<<RB, 256, 0, stream>>>(exps, rew, gt, pts, svf,
                                            esum_p, edot_p, count, vdot,
                                            ms, P);
    loss_kernel<<<1, 64, 0, stream>>>(esum_p, edot_p, vdot, count, loss_out);
}

// Round 7
// 315.906 us; speedup vs baseline: 1.0776x; 1.0123x over previous
//
#include <hip/hip_runtime.h>

#define Bb 64
#define Tt 256
#define Hh 512
#define Ww 1024
#define HW (Hh * Ww)          // 524288
#define EPSF 1e-5f

#define RB 4096               // one block per 8192-float chunk; 2 generations
#define CHUNK 8192            // svf floats owned per block (64 blocks/batch)

typedef float vf4 __attribute__((ext_vector_type(4)));

// ws layout (byte-identical footprint to prior rounds):
//   [0,256)         int    count[64]
//   [256,768)       double vdot[64]
//   [768,17152)     float  esum_p[4096]   (float partials are EXACT: each is
//   [17152,33536)   float  edot_p[4096]    itself a block-computed fp32 value)
// Everything is written before it is read -> no ws memset needed.

// ---------------------------------------------------------------------------
// Point computation (bit-identical to the reference at fp32)
// ---------------------------------------------------------------------------
__device__ __forceinline__ void comp_pt(const float* __restrict__ gt, int b,
                                        int idx, int ms, int segN,
                                        float& px, float& py) {
    if (idx < segN) {
        int seg = idx / ms;
        int k = idx - seg * ms;
        const float* g0 = gt + (size_t)(b * Tt + seg) * 9;
        float sx = g0[2] * 0.5f, sy = g0[5] * 0.5f;
        float ex = g0[11] * 0.5f, ey = g0[14] * 0.5f;
        float t = (ms > 1) ? (float)k / (float)(ms - 1) : 0.0f;
        px = __fadd_rn(sx, __fmul_rn(t, __fsub_rn(ex, sx)));
        py = __fadd_rn(sy, __fmul_rn(t, __fsub_rn(ey, sy)));
    } else {
        const float* g0 = gt + (size_t)(b * Tt + (Tt - 1)) * 9;
        px = g0[2] * 0.5f;
        py = g0[5] * 0.5f;
    }
}

__device__ __forceinline__ int pt_cell(float px, float py) {
    int xi = (int)fminf(fmaxf(px, 0.0f), (float)(Hh - 1));
    int yi = (int)fminf(fmaxf(py, 0.0f), (float)(Ww - 1));
    return xi * Ww + yi;
}

// ---------------------------------------------------------------------------
// Combined kernel: grid = 4096 blocks = TWO generations (round 5: 117 us,
// Occupancy 78%). Single change vs round 5: phase A pins all 16 loads
// (8 exps + 8 rew) BEFORE any consumption via sched_barrier(0). Round-5
// counters showed VGPR_Count=32, proving the compiler collapsed the intended
// 8-deep batch to ~4 loads in flight per wave. This tests whether the
// ~2.5 TB/s read cap is per-wave-MLP-limited (expect <=105 us) or a HW
// queue/MSHR cap (expect null; then the kernel is at its empirical read
// floor of 268 MB / 2.5 TB/s ~= 107 us and we declare roofline).
// Diagnostic that the pin armed: VGPR_Count should jump to ~80-100.
// Block (b = blk>>6, c = blk&63) owns svf chunk [c*8192, (c+1)*8192) of
// batch b. Phase order preserved (loads first; fill stores drain under the
// dedup ALU + barrier; NT stores stay reverted -- they cost 20 us).
// Chunks are disjoint -> no atomics, no cross-block races.
// ---------------------------------------------------------------------------
__global__ __launch_bounds__(256) void combined_kernel(
        const float* __restrict__ exps, const float* __restrict__ rew,
        const float* __restrict__ gt,
        float* __restrict__ pts, float* __restrict__ svf,
        float* __restrict__ esum_p, float* __restrict__ edot_p,
        int* __restrict__ count_out, double* __restrict__ vdot_out,
        int ms, int P) {
    int blk = blockIdx.x;
    int b = blk >> 6;
    int c = blk & 63;
    bool isScat = (c == b);          // designated scatter block for batch b
    int segN = (Tt - 1) * ms;
    size_t base = (size_t)b * HW + (size_t)c * CHUNK;

    // ---- phase A: streaming reduce. All 16 loads issue, THEN the scheduler
    // barrier, THEN consumption -- forces 16 float4 in flight per wave.
    // Arithmetic (order of adds/fmas) is identical to round 5 -> absmax 0.
    float es = 0.0f, ed = 0.0f;
    {
        const vf4* e4 = (const vf4*)(exps + base) + threadIdx.x;
        const vf4* r4 = (const vf4*)(rew  + base) + threadIdx.x;
        vf4 ev[8], rv[8];
        #pragma unroll
        for (int k = 0; k < 8; ++k) ev[k] = e4[k * 256];
        #pragma unroll
        for (int k = 0; k < 8; ++k) rv[k] = r4[k * 256];
        __builtin_amdgcn_sched_barrier(0);   // pin: no consume before issue
        #pragma unroll
        for (int k = 0; k < 8; ++k) {
            vf4 e = ev[k], r = rv[k];
            es += (e.x + e.y) + (e.z + e.w);
            ed += (e.x * r.x + e.y * r.y) + (e.z * r.z + e.w * r.w);
        }
    }
    for (int off = 32; off; off >>= 1) {
        es += __shfl_down(es, off);
        ed += __shfl_down(ed, off);
    }

    // ---- phase B: plain zero-fill (fire-and-forget; drains during phase C,
    // the barrier, and other blocks' phase A). svf = out+1 is only
    // 4B-aligned: peel head/tail scalars around the aligned vf4 body.
    {
        float* p = svf + base;
        int head = (int)((16 - ((uintptr_t)p & 15)) & 15) >> 2;  // 0..3
        int nv   = (CHUNK - head) >> 2;
        int tail = CHUNK - head - (nv << 2);
        if ((int)threadIdx.x < head) p[threadIdx.x] = 0.0f;
        if ((int)threadIdx.x < tail) p[head + (nv << 2) + threadIdx.x] = 0.0f;
        vf4* v4 = (vf4*)(p + head);
        vf4 z = {0.0f, 0.0f, 0.0f, 0.0f};
        for (int k = (int)threadIdx.x; k < nv; k += 256) v4[k] = z;
    }

    // ---- phase C: per-batch dedup count; designated block also scatters pts
    // and gathers vdot (identical arithmetic to prior rounds).
    int myCount = 0;
    float myV = 0.0f;
    for (int idx = threadIdx.x; idx < P; idx += 256) {
        float px, py;
        comp_pt(gt, b, idx, ms, segN, px, py);
        int cell = pt_cell(px, py);
        bool claim;
        if (idx == 0) {
            claim = true;
        } else {
            float qx, qy;
            comp_pt(gt, b, idx - 1, ms, segN, qx, qy);
            claim = (pt_cell(qx, qy) != cell);
        }
        myCount += claim ? 1 : 0;
        if (isScat) {
            size_t pi = ((size_t)b * P + idx) * 2;
            pts[pi]     = px;
            pts[pi + 1] = py;
            if (claim) myV += rew[(size_t)b * HW + cell];
        }
    }
    for (int off = 32; off; off >>= 1) {
        myCount += __shfl_down(myCount, off);
        myV     += __shfl_down(myV, off);
    }

    __shared__ float s_es[4], s_ed[4];
    __shared__ float sv[4];
    __shared__ int   sc2[4];
    int lane = threadIdx.x & 63, wv = threadIdx.x >> 6;
    if (lane == 0) { s_es[wv] = es; s_ed[wv] = ed; sc2[wv] = myCount; sv[wv] = myV; }
    __syncthreads();   // publishes LDS partials AND drains phase-B stores
    if (threadIdx.x == 0) {
        esum_p[blk] = (s_es[0] + s_es[1]) + (s_es[2] + s_es[3]);
        edot_p[blk] = (s_ed[0] + s_ed[1]) + (s_ed[2] + s_ed[3]);
        if (isScat) {
            int tot  = (sc2[0] + sc2[1]) + (sc2[2] + sc2[3]);
            float tv = (sv[0] + sv[1]) + (sv[2] + sv[3]);
            count_out[b] = tot;
            vdot_out[b]  = (double)tv;
        }
    }
    int tot = (sc2[0] + sc2[1]) + (sc2[2] + sc2[3]);
    float recip = 1.0f / ((float)tot + EPSF);

    // ---- phase D: write recip at visited cells inside this chunk
    // (duplicates write the identical value; zeros already laid down)
    int lo = c * CHUNK, hi = lo + CHUNK;
    for (int idx = threadIdx.x; idx < P; idx += 256) {
        float px, py;
        comp_pt(gt, b, idx, ms, segN, px, py);
        int cell = pt_cell(px, py);
        if (cell >= lo && cell < hi)
            svf[(size_t)b * HW + cell] = recip;
    }
}

// ---------------------------------------------------------------------------
// Loss kernel (64 float partials per batch; accumulation stays double)
// ---------------------------------------------------------------------------
__global__ void loss_kernel(const float* __restrict__ esum_p,
                            const float* __restrict__ edot_p,
                            const double* __restrict__ vdot,
                            const int* __restrict__ count,
                            float* __restrict__ loss_out) {
    int b = threadIdx.x;  // 64 threads = 1 wave
    double es = 0.0, ed = 0.0;
    #pragma unroll 8
    for (int c = 0; c < 64; ++c) {
        es += (double)esum_p[b * 64 + c];
        ed += (double)edot_p[b * 64 + c];
    }
    double e = ed / (es + 1e-5);
    double v = vdot[b] / ((double)count[b] + 1e-5);
    double term = e - v;
    for (int off = 32; off; off >>= 1) term += __shfl_down(term, off);
    if (b == 0) loss_out[0] = (float)(term / (double)Bb);
}

extern "C" void kernel_launch(void* const* d_in, const int* in_sizes, int n_in,
                              void* d_out, int out_size, void* d_ws, size_t ws_size,
                              hipStream_t stream) {
    const float* gt   = (const float*)d_in[0];
    const float* exps = (const float*)d_in[1];
    const float* rew  = (const float*)d_in[2];
    float* out = (float*)d_out;

    float* loss_out = out;
    float* svf = out + 1;
    int P  = (out_size - 1 - Bb * HW) / (Bb * 2);
    int ms = (P - 1) / (Tt - 1);
    float* pts = out + 1 + (size_t)Bb * HW;

    int*    count  = (int*)d_ws;
    double* vdot   = (double*)((char*)d_ws + 256);
    float*  esum_p = (float*)((char*)d_ws + 768);
    float*  edot_p = (float*)((char*)d_ws + 17152);

    combined_kernel<<<RB, 256, 0, stream>>>(exps, rew, gt, pts, svf,
                                            esum_p, edot_p, count, vdot,
                                            ms, P);
    loss_kernel<<<1, 64, 0, stream>>>(esum_p, edot_p, vdot, count, loss_out);
}